// Round 7
// baseline (330.492 us; speedup 1.0000x reference)
//
#include <hip/hip_runtime.h>

#define EPSV 1e-5f

typedef _Float16 half2_t __attribute__((ext_vector_type(2)));
typedef _Float16 half4_t __attribute__((ext_vector_type(4)));
typedef _Float16 half8_t __attribute__((ext_vector_type(8)));
typedef float float4_t __attribute__((ext_vector_type(4)));

__device__ __forceinline__ float wave_red(float v) {
#pragma unroll
  for (int off = 32; off > 0; off >>= 1) v += __shfl_xor(v, off, 64);
  return v;
}

// ---- CSR build ------------------------------------------------------------
// k_count: unsliced — atomic RMWs dirty-merge in cache (no 64B write-amp),
// and slicing's 8x edge re-read costs more than it saves (R5 post-mortem).
// k_fill: XCD-sliced (blockIdx&7 ~ XCD) — its 4B scatter stores DO suffer
// 64B-line write amplification (52MB -> ~4MB) unless each XCD's writes stay
// in a ~400KB L2-resident csr range.

__global__ void k_count(const int* __restrict__ dst, int* __restrict__ deg, int E) {
  int e = blockIdx.x * blockDim.x + threadIdx.x;
  if (e < E) atomicAdd(&deg[dst[e]], 1);
}

__global__ __launch_bounds__(256) void k_fill(const int* __restrict__ src,
                                              const int* __restrict__ dst,
                                              int* __restrict__ cursor,
                                              int* __restrict__ csr_src, int E, int N) {
  int slice = blockIdx.x & 7;
  int lo = (int)(((long long)N * slice) >> 3);
  int hi = (int)(((long long)N * (slice + 1)) >> 3);
  int r = (blockIdx.x >> 3) * blockDim.x + threadIdx.x;
  int stride = (gridDim.x >> 3) * blockDim.x;
  for (int e = r; e < E; e += stride) {
    int d = __builtin_nontemporal_load(&dst[e]);
    if (d >= lo && d < hi) {
      int s = __builtin_nontemporal_load(&src[e]);
      int pos = atomicAdd(&cursor[d], 1);
      csr_src[pos] = s;
    }
  }
}

__global__ __launch_bounds__(256) void k_partial(const int* __restrict__ deg,
                                                 int* __restrict__ partials, int N) {
  __shared__ int red[256];
  int i = blockIdx.x * 256 + threadIdx.x;
  red[threadIdx.x] = (i < N) ? deg[i] : 0;
  __syncthreads();
#pragma unroll
  for (int off = 128; off > 0; off >>= 1) {
    if (threadIdx.x < off) red[threadIdx.x] += red[threadIdx.x + off];
    __syncthreads();
  }
  if (threadIdx.x == 0) partials[blockIdx.x] = red[0];
}

__global__ __launch_bounds__(256) void k_scan_partials(int* __restrict__ partials, int nb) {
  __shared__ int s[256];
  int t = threadIdx.x;
  s[t] = (t < nb) ? partials[t] : 0;
  __syncthreads();
#pragma unroll
  for (int off = 1; off < 256; off <<= 1) {
    int v = (t >= off) ? s[t - off] : 0;
    __syncthreads();
    s[t] += v;
    __syncthreads();
  }
  if (t < nb) partials[t] = (t > 0) ? s[t - 1] : 0;  // exclusive
}

__global__ __launch_bounds__(256) void k_write(const int* __restrict__ deg,
                                               const int* __restrict__ partials,
                                               int* __restrict__ row_start,
                                               int* __restrict__ cursor,
                                               float* __restrict__ dinv, int N) {
  __shared__ int s[256];
  int t = threadIdx.x;
  int i = blockIdx.x * 256 + t;
  int d = (i < N) ? deg[i] : 0;
  s[t] = d;
  __syncthreads();
#pragma unroll
  for (int off = 1; off < 256; off <<= 1) {
    int v = (t >= off) ? s[t - off] : 0;
    __syncthreads();
    s[t] += v;
    __syncthreads();
  }
  if (i < N) {
    int excl = partials[blockIdx.x] + s[t] - d;  // inclusive - self
    row_start[i] = excl;
    cursor[i] = excl;
    dinv[i] = rsqrtf((float)(d + 1));  // deg includes self-loop; > 0
  }
}

// ---- W pre-swizzle (all 3 weights, one launch) ----------------------------
// Wh[((nb*4+ks)*64 + lane)*8 + j] = W[ks*32 + (lane>>4)*8 + j][nb*16 + (lane&15)]

__global__ __launch_bounds__(256) void k_wprep_all(
    const float* __restrict__ W1, const float* __restrict__ W2,
    const float* __restrict__ W3, _Float16* __restrict__ Wh1,
    _Float16* __restrict__ Wh2, _Float16* __restrict__ Wh3) {
  int bid = blockIdx.x;
  const float* W;
  _Float16* Wh;
  int COLS, t;
  if (bid < 8) { W = W1; Wh = Wh1; COLS = 128; t = bid * 256 + threadIdx.x; }
  else if (bid < 16) { W = W2; Wh = Wh2; COLS = 128; t = (bid - 8) * 256 + threadIdx.x; }
  else { W = W3; Wh = Wh3; COLS = 64; t = (bid - 16) * 256 + threadIdx.x; }
  int NT = (COLS / 16) * 4 * 64;
  if (t >= NT) return;
  int lane = t & 63;
  int ks = (t >> 6) & 3;
  int nb = t >> 8;
  int col = nb * 16 + (lane & 15);
  int k0 = ks * 32 + (lane >> 4) * 8;
  half8_t v;
#pragma unroll
  for (int j = 0; j < 8; j++) v[j] = (_Float16)W[(size_t)(k0 + j) * COLS + col];
  *(half8_t*)&Wh[(size_t)t * 8] = v;
}

// ---- GEMM via MFMA: [N x 128] -> fp16 y = dinv[row] * (A @ W) -------------
// One wave per 16 rows x COLS. A direct from global (fp32 cvt or fp16
// straight half8); B from pre-swizzled Wh (L1/L2-resident); fp32 MFMA acc.
// D layout: row = quad*4 + reg, col = lane&15.

template <int COLS, typename AT>
__global__ __launch_bounds__(256) void k_gemm_mfma(const AT* __restrict__ A,
                                                   const _Float16* __restrict__ Wh,
                                                   const float* __restrict__ dinv,
                                                   _Float16* __restrict__ out, int N) {
  constexpr int NB = COLS / 16;
  int lane = threadIdx.x & 63;
  int w = threadIdx.x >> 6;
  int quad = lane >> 4;
  int mrow = blockIdx.x * 64 + w * 16 + (lane & 15);
  half8_t af[4];
  if (mrow < N) {
    const AT* ap = A + (size_t)mrow * 128 + quad * 8;
#pragma unroll
    for (int ks = 0; ks < 4; ks++) {
      if constexpr (sizeof(AT) == 2) {
        af[ks] = *(const half8_t*)(ap + ks * 32);
      } else {
        float4 f0 = *(const float4*)(ap + ks * 32);
        float4 f1 = *(const float4*)(ap + ks * 32 + 4);
        af[ks][0] = (_Float16)f0.x; af[ks][1] = (_Float16)f0.y;
        af[ks][2] = (_Float16)f0.z; af[ks][3] = (_Float16)f0.w;
        af[ks][4] = (_Float16)f1.x; af[ks][5] = (_Float16)f1.y;
        af[ks][6] = (_Float16)f1.z; af[ks][7] = (_Float16)f1.w;
      }
    }
  } else {
#pragma unroll
    for (int ks = 0; ks < 4; ks++)
#pragma unroll
      for (int j = 0; j < 8; j++) af[ks][j] = (_Float16)0.f;
  }
  float4_t acc[NB];
#pragma unroll
  for (int nb = 0; nb < NB; nb++) acc[nb] = (float4_t){0.f, 0.f, 0.f, 0.f};
#pragma unroll
  for (int nb = 0; nb < NB; nb++) {
#pragma unroll
    for (int ks = 0; ks < 4; ks++) {
      half8_t bf = *(const half8_t*)&Wh[(size_t)((nb * 4 + ks) * 64 + lane) * 8];
      acc[nb] = __builtin_amdgcn_mfma_f32_16x16x32_f16(af[ks], bf, acc[nb], 0, 0, 0);
    }
  }
  int orow0 = blockIdx.x * 64 + w * 16 + quad * 4;
#pragma unroll
  for (int r = 0; r < 4; r++) {
    int row = orow0 + r;
    if (row < N) {
      float dv = dinv[row];
#pragma unroll
      for (int nb = 0; nb < NB; nb++)
        out[(size_t)row * COLS + nb * 16 + (lane & 15)] = (_Float16)(acc[nb][r] * dv);
    }
  }
}

// ---- Aggregation + bias + ReLU + LayerNorm, 128 dims, fp16 out ------------
// Wave per node. Paired-edge gathers: lanes 0-31 gather edge j (half4 = 4
// dims/lane), lanes 32-63 edge j+1; one shfl_xor(.,32) combines. 512B per
// load instruction (2 edges), half the broadcast/addr work per edge.

__global__ __launch_bounds__(256) void k_agg_ln(
    const _Float16* __restrict__ y, const int* __restrict__ csr,
    const int* __restrict__ row_start, const int* __restrict__ deg,
    const float* __restrict__ dinv, const float* __restrict__ b,
    const float* __restrict__ g, const float* __restrict__ be,
    _Float16* __restrict__ h, int N) {
  int node = blockIdx.x * 4 + (threadIdx.x >> 6);
  if (node >= N) return;
  int lane = threadIdx.x & 63;
  int half = lane >> 5;
  int l32 = lane & 31;  // dims [4*l32, 4*l32+4)
  const half4_t* y4 = (const half4_t*)y;  // row = 32 x half4
  int s0 = row_start[node];
  int cnt = deg[node];
  int idx = 0;
  if (lane < cnt) idx = csr[s0 + lane];  // lane covers edge `lane`
  float a0 = 0.f, a1 = 0.f, a2 = 0.f, a3 = 0.f;
  int m = min(cnt, 64);
  for (int j = 0; j < m; j += 2) {
    int e = j + half;
    int s = __shfl(idx, min(e, m - 1), 64);  // bpermute (per-half src lane)
    half4_t u = y4[(size_t)s * 32 + l32];
    float wv = (e < m) ? 1.f : 0.f;  // mask the odd-tail duplicate
    a0 = fmaf(wv, (float)u[0], a0);
    a1 = fmaf(wv, (float)u[1], a1);
    a2 = fmaf(wv, (float)u[2], a2);
    a3 = fmaf(wv, (float)u[3], a3);
  }
  // combine the two halves (each lane then holds full edge-sums for its dims)
  a0 += __shfl_xor(a0, 32, 64);
  a1 += __shfl_xor(a1, 32, 64);
  a2 += __shfl_xor(a2, 32, 64);
  a3 += __shfl_xor(a3, 32, 64);
  for (int k = 64; k < cnt; k++) {  // deg>64 fallback (post-combine: add once)
    int s = csr[s0 + k];
    half4_t u = y4[(size_t)s * 32 + l32];
    a0 += (float)u[0]; a1 += (float)u[1]; a2 += (float)u[2]; a3 += (float)u[3];
  }
  half4_t v = y4[(size_t)node * 32 + l32];  // self term
  a0 += (float)v[0]; a1 += (float)v[1]; a2 += (float)v[2]; a3 += (float)v[3];
  float di = dinv[node];
  float4 bb = ((const float4*)b)[l32];
  a0 = fmaxf(fmaf(a0, di, bb.x), 0.f);
  a1 = fmaxf(fmaf(a1, di, bb.y), 0.f);
  a2 = fmaxf(fmaf(a2, di, bb.z), 0.f);
  a3 = fmaxf(fmaf(a3, di, bb.w), 0.f);
  // LN over 128 dims; both halves replicated -> full-wave red counts x2
  float mean = wave_red(a0 + a1 + a2 + a3) * (1.f / 256.f);
  float d0 = a0 - mean, d1 = a1 - mean, d2 = a2 - mean, d3 = a3 - mean;
  float var = wave_red(d0 * d0 + d1 * d1 + d2 * d2 + d3 * d3) * (1.f / 256.f);
  float rstd = rsqrtf(var + EPSV);
  float4 gg = ((const float4*)g)[l32];
  float4 ee = ((const float4*)be)[l32];
  if (half == 0) {
    half4_t o;
    o[0] = (_Float16)(d0 * rstd * gg.x + ee.x);
    o[1] = (_Float16)(d1 * rstd * gg.y + ee.y);
    o[2] = (_Float16)(d2 * rstd * gg.z + ee.z);
    o[3] = (_Float16)(d3 * rstd * gg.w + ee.w);
    ((half4_t*)h)[(size_t)node * 32 + l32] = o;
  }
}

// ---- Final aggregation, 64 dims, + bias only ------------------------------
// Same paired-edge structure; lane covers dims [2*l32, 2*l32+2) as half2.

__global__ __launch_bounds__(256) void k_agg_out(
    const _Float16* __restrict__ y, const int* __restrict__ csr,
    const int* __restrict__ row_start, const int* __restrict__ deg,
    const float* __restrict__ dinv, const float* __restrict__ b,
    float* __restrict__ out, int N) {
  int node = blockIdx.x * 4 + (threadIdx.x >> 6);
  if (node >= N) return;
  int lane = threadIdx.x & 63;
  int half = lane >> 5;
  int l32 = lane & 31;
  const half2_t* y2 = (const half2_t*)y;  // row = 32 x half2
  int s0 = row_start[node];
  int cnt = deg[node];
  int idx = 0;
  if (lane < cnt) idx = csr[s0 + lane];
  float a0 = 0.f, a1 = 0.f;
  int m = min(cnt, 64);
  for (int j = 0; j < m; j += 2) {
    int e = j + half;
    int s = __shfl(idx, min(e, m - 1), 64);
    half2_t u = y2[(size_t)s * 32 + l32];
    float wv = (e < m) ? 1.f : 0.f;
    a0 = fmaf(wv, (float)u[0], a0);
    a1 = fmaf(wv, (float)u[1], a1);
  }
  a0 += __shfl_xor(a0, 32, 64);
  a1 += __shfl_xor(a1, 32, 64);
  for (int k = 64; k < cnt; k++) {
    int s = csr[s0 + k];
    half2_t u = y2[(size_t)s * 32 + l32];
    a0 += (float)u[0]; a1 += (float)u[1];
  }
  half2_t v = y2[(size_t)node * 32 + l32];  // self
  a0 += (float)v[0]; a1 += (float)v[1];
  float di = dinv[node];
  float2 bb = ((const float2*)b)[l32];
  if (half == 0) {
    float2 o;
    o.x = fmaf(a0, di, bb.x);
    o.y = fmaf(a1, di, bb.y);
    ((float2*)out)[(size_t)node * 32 + l32] = o;
  }
}

// ---- Launch ---------------------------------------------------------------

extern "C" void kernel_launch(void* const* d_in, const int* in_sizes, int n_in,
                              void* d_out, int out_size, void* d_ws, size_t ws_size,
                              hipStream_t stream) {
  const float* x = (const float*)d_in[0];
  const int* ei = (const int*)d_in[1];
  const float* W1 = (const float*)d_in[2];
  const float* b1 = (const float*)d_in[3];
  const float* W2 = (const float*)d_in[4];
  const float* b2 = (const float*)d_in[5];
  const float* W3 = (const float*)d_in[6];
  const float* b3 = (const float*)d_in[7];
  const float* g1 = (const float*)d_in[8];
  const float* be1 = (const float*)d_in[9];
  const float* g2 = (const float*)d_in[10];
  const float* be2 = (const float*)d_in[11];

  int N = in_sizes[0] / 128;
  int E = in_sizes[1] / 2;
  const int* srcs = ei;
  const int* dsts = ei + E;

  char* ws = (char*)d_ws;
  size_t off = 0;
  auto alloc = [&](size_t bytes) -> char* {
    char* p = ws + off;
    off = (off + bytes + 255) & ~(size_t)255;
    return p;
  };
  float* dinv = (float*)alloc((size_t)N * 4);
  int* deg = (int*)alloc((size_t)N * 4);
  int* row_start = (int*)alloc((size_t)N * 4);
  int* cursor = (int*)alloc((size_t)N * 4);
  int* partials = (int*)alloc(256 * 4);
  int* csr = (int*)alloc((size_t)E * 4);
  _Float16* y = (_Float16*)alloc((size_t)N * 128 * 2);
  _Float16* h = (_Float16*)alloc((size_t)N * 128 * 2);
  _Float16* Wh1 = (_Float16*)alloc(128 * 128 * 2);
  _Float16* Wh2 = (_Float16*)alloc(128 * 128 * 2);
  _Float16* Wh3 = (_Float16*)alloc(128 * 64 * 2);

  hipMemsetAsync(deg, 0, (size_t)N * sizeof(int), stream);
  int sb = (N + 255) / 256;
  k_count<<<(E + 255) / 256, 256, 0, stream>>>(dsts, deg, E);
  k_wprep_all<<<20, 256, 0, stream>>>(W1, W2, W3, Wh1, Wh2, Wh3);
  k_partial<<<sb, 256, 0, stream>>>(deg, partials, N);
  k_scan_partials<<<1, 256, 0, stream>>>(partials, sb);
  k_write<<<sb, 256, 0, stream>>>(deg, partials, row_start, cursor, dinv, N);
  k_fill<<<2048, 256, 0, stream>>>(srcs, dsts, cursor, csr, E, N);

  int gb = (N + 63) / 64;  // 64 rows per block (4 waves x 16 rows)
  int nb = (N + 3) / 4;    // 4 waves (nodes) per block

  // Layer 1
  k_gemm_mfma<128, float><<<gb, 256, 0, stream>>>(x, Wh1, dinv, y, N);
  k_agg_ln<<<nb, 256, 0, stream>>>(y, csr, row_start, deg, dinv, b1, g1, be1, h, N);
  // Layer 2
  k_gemm_mfma<128, _Float16><<<gb, 256, 0, stream>>>(h, Wh2, dinv, y, N);
  k_agg_ln<<<nb, 256, 0, stream>>>(y, csr, row_start, deg, dinv, b2, g2, be2, h, N);
  // Layer 3
  k_gemm_mfma<64, _Float16><<<gb, 256, 0, stream>>>(h, Wh3, dinv, y, N);
  k_agg_out<<<nb, 256, 0, stream>>>(y, csr, row_start, deg, dinv, b3, (float*)d_out, N);
}

// Round 8
// 311.132 us; speedup vs baseline: 1.0622x; 1.0622x over previous
//
#include <hip/hip_runtime.h>

#define EPSV 1e-5f

typedef _Float16 half2_t __attribute__((ext_vector_type(2)));
typedef _Float16 half8_t __attribute__((ext_vector_type(8)));
typedef float float4_t __attribute__((ext_vector_type(4)));

__device__ __forceinline__ float wave_red(float v) {
#pragma unroll
  for (int off = 32; off > 0; off >>= 1) v += __shfl_xor(v, off, 64);
  return v;
}

// ---- CSR build ------------------------------------------------------------
// BOTH k_count and k_fill are XCD-sliced (blockIdx&7 ~ XCD). Evidence (R7):
// unsliced k_count showed 25MB WRITE for a 200KB deg array — device-scope
// atomic lines ping-pong between the 8 non-coherent L2s. Slicing keeps each
// XCD's atomics/stores in a private ~400KB L2-resident range (one final
// writeback). All slices stream the whole edge list; L3 absorbs re-reads.

__global__ __launch_bounds__(256) void k_count(const int* __restrict__ dst,
                                               int* __restrict__ deg, int E, int N) {
  int slice = blockIdx.x & 7;
  int lo = (int)(((long long)N * slice) >> 3);
  int hi = (int)(((long long)N * (slice + 1)) >> 3);
  int r = (blockIdx.x >> 3) * blockDim.x + threadIdx.x;
  int stride = (gridDim.x >> 3) * blockDim.x;
  for (int e = r; e < E; e += stride) {
    int d = __builtin_nontemporal_load(&dst[e]);
    if (d >= lo && d < hi) atomicAdd(&deg[d], 1);
  }
}

__global__ __launch_bounds__(256) void k_fill(const int* __restrict__ src,
                                              const int* __restrict__ dst,
                                              int* __restrict__ cursor,
                                              int* __restrict__ csr_src, int E, int N) {
  int slice = blockIdx.x & 7;
  int lo = (int)(((long long)N * slice) >> 3);
  int hi = (int)(((long long)N * (slice + 1)) >> 3);
  int r = (blockIdx.x >> 3) * blockDim.x + threadIdx.x;
  int stride = (gridDim.x >> 3) * blockDim.x;
  for (int e = r; e < E; e += stride) {
    int d = __builtin_nontemporal_load(&dst[e]);
    if (d >= lo && d < hi) {
      int s = __builtin_nontemporal_load(&src[e]);
      int pos = atomicAdd(&cursor[d], 1);
      csr_src[pos] = s;
    }
  }
}

__global__ __launch_bounds__(256) void k_partial(const int* __restrict__ deg,
                                                 int* __restrict__ partials, int N) {
  __shared__ int red[256];
  int i = blockIdx.x * 256 + threadIdx.x;
  red[threadIdx.x] = (i < N) ? deg[i] : 0;
  __syncthreads();
#pragma unroll
  for (int off = 128; off > 0; off >>= 1) {
    if (threadIdx.x < off) red[threadIdx.x] += red[threadIdx.x + off];
    __syncthreads();
  }
  if (threadIdx.x == 0) partials[blockIdx.x] = red[0];
}

__global__ __launch_bounds__(256) void k_scan_partials(int* __restrict__ partials, int nb) {
  __shared__ int s[256];
  int t = threadIdx.x;
  s[t] = (t < nb) ? partials[t] : 0;
  __syncthreads();
#pragma unroll
  for (int off = 1; off < 256; off <<= 1) {
    int v = (t >= off) ? s[t - off] : 0;
    __syncthreads();
    s[t] += v;
    __syncthreads();
  }
  if (t < nb) partials[t] = (t > 0) ? s[t - 1] : 0;  // exclusive
}

__global__ __launch_bounds__(256) void k_write(const int* __restrict__ deg,
                                               const int* __restrict__ partials,
                                               int* __restrict__ row_start,
                                               int* __restrict__ cursor,
                                               float* __restrict__ dinv, int N) {
  __shared__ int s[256];
  int t = threadIdx.x;
  int i = blockIdx.x * 256 + t;
  int d = (i < N) ? deg[i] : 0;
  s[t] = d;
  __syncthreads();
#pragma unroll
  for (int off = 1; off < 256; off <<= 1) {
    int v = (t >= off) ? s[t - off] : 0;
    __syncthreads();
    s[t] += v;
    __syncthreads();
  }
  if (i < N) {
    int excl = partials[blockIdx.x] + s[t] - d;  // inclusive - self
    row_start[i] = excl;
    cursor[i] = excl;
    dinv[i] = rsqrtf((float)(d + 1));  // deg includes self-loop; > 0
  }
}

// ---- W pre-swizzle (all 3 weights, one launch) ----------------------------
// Wh[((nb*4+ks)*64 + lane)*8 + j] = W[ks*32 + (lane>>4)*8 + j][nb*16 + (lane&15)]

__global__ __launch_bounds__(256) void k_wprep_all(
    const float* __restrict__ W1, const float* __restrict__ W2,
    const float* __restrict__ W3, _Float16* __restrict__ Wh1,
    _Float16* __restrict__ Wh2, _Float16* __restrict__ Wh3) {
  int bid = blockIdx.x;
  const float* W;
  _Float16* Wh;
  int COLS, t;
  if (bid < 8) { W = W1; Wh = Wh1; COLS = 128; t = bid * 256 + threadIdx.x; }
  else if (bid < 16) { W = W2; Wh = Wh2; COLS = 128; t = (bid - 8) * 256 + threadIdx.x; }
  else { W = W3; Wh = Wh3; COLS = 64; t = (bid - 16) * 256 + threadIdx.x; }
  int NT = (COLS / 16) * 4 * 64;
  if (t >= NT) return;
  int lane = t & 63;
  int ks = (t >> 6) & 3;
  int nb = t >> 8;
  int col = nb * 16 + (lane & 15);
  int k0 = ks * 32 + (lane >> 4) * 8;
  half8_t v;
#pragma unroll
  for (int j = 0; j < 8; j++) v[j] = (_Float16)W[(size_t)(k0 + j) * COLS + col];
  *(half8_t*)&Wh[(size_t)t * 8] = v;
}

// ---- GEMM via MFMA: [N x 128] -> fp16 y = dinv[row] * (A @ W) -------------
// One wave per 16 rows x COLS. A direct from global (fp32 cvt or fp16
// straight half8); B from pre-swizzled Wh (L1/L2-resident); fp32 MFMA acc.
// D layout: row = quad*4 + reg, col = lane&15.

template <int COLS, typename AT>
__global__ __launch_bounds__(256) void k_gemm_mfma(const AT* __restrict__ A,
                                                   const _Float16* __restrict__ Wh,
                                                   const float* __restrict__ dinv,
                                                   _Float16* __restrict__ out, int N) {
  constexpr int NB = COLS / 16;
  int lane = threadIdx.x & 63;
  int w = threadIdx.x >> 6;
  int quad = lane >> 4;
  int mrow = blockIdx.x * 64 + w * 16 + (lane & 15);
  half8_t af[4];
  if (mrow < N) {
    const AT* ap = A + (size_t)mrow * 128 + quad * 8;
#pragma unroll
    for (int ks = 0; ks < 4; ks++) {
      if constexpr (sizeof(AT) == 2) {
        af[ks] = *(const half8_t*)(ap + ks * 32);
      } else {
        float4 f0 = *(const float4*)(ap + ks * 32);
        float4 f1 = *(const float4*)(ap + ks * 32 + 4);
        af[ks][0] = (_Float16)f0.x; af[ks][1] = (_Float16)f0.y;
        af[ks][2] = (_Float16)f0.z; af[ks][3] = (_Float16)f0.w;
        af[ks][4] = (_Float16)f1.x; af[ks][5] = (_Float16)f1.y;
        af[ks][6] = (_Float16)f1.z; af[ks][7] = (_Float16)f1.w;
      }
    }
  } else {
#pragma unroll
    for (int ks = 0; ks < 4; ks++)
#pragma unroll
      for (int j = 0; j < 8; j++) af[ks][j] = (_Float16)0.f;
  }
  float4_t acc[NB];
#pragma unroll
  for (int nb = 0; nb < NB; nb++) acc[nb] = (float4_t){0.f, 0.f, 0.f, 0.f};
#pragma unroll
  for (int nb = 0; nb < NB; nb++) {
#pragma unroll
    for (int ks = 0; ks < 4; ks++) {
      half8_t bf = *(const half8_t*)&Wh[(size_t)((nb * 4 + ks) * 64 + lane) * 8];
      acc[nb] = __builtin_amdgcn_mfma_f32_16x16x32_f16(af[ks], bf, acc[nb], 0, 0, 0);
    }
  }
  int orow0 = blockIdx.x * 64 + w * 16 + quad * 4;
#pragma unroll
  for (int r = 0; r < 4; r++) {
    int row = orow0 + r;
    if (row < N) {
      float dv = dinv[row];
#pragma unroll
      for (int nb = 0; nb < NB; nb++)
        out[(size_t)row * COLS + nb * 16 + (lane & 15)] = (_Float16)(acc[nb][r] * dv);
    }
  }
}

// ---- Aggregation + bias + ReLU + LayerNorm, 128 dims, fp16 out ------------
// R6-proven structure: wave per node, lane owns dims {2l,2l+1}; 64 neighbor
// indices in ONE coalesced load, broadcast via wave-uniform __shfl (readlane
// -> SGPR gather base). 8-deep unroll = 8 independent 256B gathers in flight
// per wave (the kernel is miss-parallelism bound, not BW bound — R7 PMC).

__global__ __launch_bounds__(256) void k_agg_ln(
    const _Float16* __restrict__ y, const int* __restrict__ csr,
    const int* __restrict__ row_start, const int* __restrict__ deg,
    const float* __restrict__ dinv, const float* __restrict__ b,
    const float* __restrict__ g, const float* __restrict__ be,
    _Float16* __restrict__ h, int N) {
  int node = blockIdx.x * 4 + (threadIdx.x >> 6);
  if (node >= N) return;
  int lane = threadIdx.x & 63;
  const half2_t* y2 = (const half2_t*)y;
  int s0 = row_start[node];
  int cnt = deg[node];
  int idx = 0;
  if (lane < cnt) idx = csr[s0 + lane];  // one load covers up to 64 edges
  half2_t v = y2[(size_t)node * 64 + lane];  // self term y[i]
  float ax0 = (float)v[0], ay0 = (float)v[1];
  float ax1 = 0.f, ay1 = 0.f, ax2 = 0.f, ay2 = 0.f, ax3 = 0.f, ay3 = 0.f;
  int m = min(cnt, 64);
  int j = 0;
  for (; j + 8 <= m; j += 8) {
    int sA = __shfl(idx, j, 64);
    int sB = __shfl(idx, j + 1, 64);
    int sC = __shfl(idx, j + 2, 64);
    int sD = __shfl(idx, j + 3, 64);
    int sE = __shfl(idx, j + 4, 64);
    int sF = __shfl(idx, j + 5, 64);
    int sG = __shfl(idx, j + 6, 64);
    int sH = __shfl(idx, j + 7, 64);
    half2_t uA = y2[(size_t)sA * 64 + lane];
    half2_t uB = y2[(size_t)sB * 64 + lane];
    half2_t uC = y2[(size_t)sC * 64 + lane];
    half2_t uD = y2[(size_t)sD * 64 + lane];
    half2_t uE = y2[(size_t)sE * 64 + lane];
    half2_t uF = y2[(size_t)sF * 64 + lane];
    half2_t uG = y2[(size_t)sG * 64 + lane];
    half2_t uH = y2[(size_t)sH * 64 + lane];
    ax0 += (float)uA[0]; ay0 += (float)uA[1];
    ax1 += (float)uB[0]; ay1 += (float)uB[1];
    ax2 += (float)uC[0]; ay2 += (float)uC[1];
    ax3 += (float)uD[0]; ay3 += (float)uD[1];
    ax0 += (float)uE[0]; ay0 += (float)uE[1];
    ax1 += (float)uF[0]; ay1 += (float)uF[1];
    ax2 += (float)uG[0]; ay2 += (float)uG[1];
    ax3 += (float)uH[0]; ay3 += (float)uH[1];
  }
  for (; j < m; j++) {
    int s = __shfl(idx, j, 64);
    half2_t u = y2[(size_t)s * 64 + lane];
    ax0 += (float)u[0]; ay0 += (float)u[1];
  }
  for (int k = 64; k < cnt; k++) {  // deg>64 fallback
    int s = csr[s0 + k];
    half2_t u = y2[(size_t)s * 64 + lane];
    ax0 += (float)u[0]; ay0 += (float)u[1];
  }
  float ax = (ax0 + ax1) + (ax2 + ax3);
  float ay = (ay0 + ay1) + (ay2 + ay3);
  float di = dinv[node];
  float2 bb = ((const float2*)b)[lane];
  ax = fmaf(ax, di, bb.x);
  ay = fmaf(ay, di, bb.y);
  ax = fmaxf(ax, 0.f);
  ay = fmaxf(ay, 0.f);
  float mean = wave_red(ax + ay) * (1.f / 128.f);
  float dx = ax - mean, dy = ay - mean;
  float var = wave_red(dx * dx + dy * dy) * (1.f / 128.f);
  float rstd = rsqrtf(var + EPSV);
  float2 gg = ((const float2*)g)[lane];
  float2 ee = ((const float2*)be)[lane];
  half2_t o;
  o[0] = (_Float16)(dx * rstd * gg.x + ee.x);
  o[1] = (_Float16)(dy * rstd * gg.y + ee.y);
  ((half2_t*)h)[(size_t)node * 64 + lane] = o;
}

// ---- Final aggregation, 64 dims, + bias only ------------------------------
// Same structure; lane owns 1 dim (fp16 scalar gathers, 128B/wave).

__global__ __launch_bounds__(256) void k_agg_out(
    const _Float16* __restrict__ y, const int* __restrict__ csr,
    const int* __restrict__ row_start, const int* __restrict__ deg,
    const float* __restrict__ dinv, const float* __restrict__ b,
    float* __restrict__ out, int N) {
  int node = blockIdx.x * 4 + (threadIdx.x >> 6);
  if (node >= N) return;
  int lane = threadIdx.x & 63;
  int s0 = row_start[node];
  int cnt = deg[node];
  int idx = 0;
  if (lane < cnt) idx = csr[s0 + lane];
  float a0 = (float)y[(size_t)node * 64 + lane];  // self term
  float a1 = 0.f, a2 = 0.f, a3 = 0.f;
  int m = min(cnt, 64);
  int j = 0;
  for (; j + 8 <= m; j += 8) {
    int sA = __shfl(idx, j, 64);
    int sB = __shfl(idx, j + 1, 64);
    int sC = __shfl(idx, j + 2, 64);
    int sD = __shfl(idx, j + 3, 64);
    int sE = __shfl(idx, j + 4, 64);
    int sF = __shfl(idx, j + 5, 64);
    int sG = __shfl(idx, j + 6, 64);
    int sH = __shfl(idx, j + 7, 64);
    a0 += (float)y[(size_t)sA * 64 + lane];
    a1 += (float)y[(size_t)sB * 64 + lane];
    a2 += (float)y[(size_t)sC * 64 + lane];
    a3 += (float)y[(size_t)sD * 64 + lane];
    a0 += (float)y[(size_t)sE * 64 + lane];
    a1 += (float)y[(size_t)sF * 64 + lane];
    a2 += (float)y[(size_t)sG * 64 + lane];
    a3 += (float)y[(size_t)sH * 64 + lane];
  }
  for (; j < m; j++) {
    int s = __shfl(idx, j, 64);
    a0 += (float)y[(size_t)s * 64 + lane];
  }
  for (int k = 64; k < cnt; k++) {
    int s = csr[s0 + k];
    a0 += (float)y[(size_t)s * 64 + lane];
  }
  out[(size_t)node * 64 + lane] = ((a0 + a1) + (a2 + a3)) * dinv[node] + b[lane];
}

// ---- Launch ---------------------------------------------------------------

extern "C" void kernel_launch(void* const* d_in, const int* in_sizes, int n_in,
                              void* d_out, int out_size, void* d_ws, size_t ws_size,
                              hipStream_t stream) {
  const float* x = (const float*)d_in[0];
  const int* ei = (const int*)d_in[1];
  const float* W1 = (const float*)d_in[2];
  const float* b1 = (const float*)d_in[3];
  const float* W2 = (const float*)d_in[4];
  const float* b2 = (const float*)d_in[5];
  const float* W3 = (const float*)d_in[6];
  const float* b3 = (const float*)d_in[7];
  const float* g1 = (const float*)d_in[8];
  const float* be1 = (const float*)d_in[9];
  const float* g2 = (const float*)d_in[10];
  const float* be2 = (const float*)d_in[11];

  int N = in_sizes[0] / 128;
  int E = in_sizes[1] / 2;
  const int* srcs = ei;
  const int* dsts = ei + E;

  char* ws = (char*)d_ws;
  size_t off = 0;
  auto alloc = [&](size_t bytes) -> char* {
    char* p = ws + off;
    off = (off + bytes + 255) & ~(size_t)255;
    return p;
  };
  float* dinv = (float*)alloc((size_t)N * 4);
  int* deg = (int*)alloc((size_t)N * 4);
  int* row_start = (int*)alloc((size_t)N * 4);
  int* cursor = (int*)alloc((size_t)N * 4);
  int* partials = (int*)alloc(256 * 4);
  int* csr = (int*)alloc((size_t)E * 4);
  _Float16* y = (_Float16*)alloc((size_t)N * 128 * 2);
  _Float16* h = (_Float16*)alloc((size_t)N * 128 * 2);
  _Float16* Wh1 = (_Float16*)alloc(128 * 128 * 2);
  _Float16* Wh2 = (_Float16*)alloc(128 * 128 * 2);
  _Float16* Wh3 = (_Float16*)alloc(128 * 64 * 2);

  hipMemsetAsync(deg, 0, (size_t)N * sizeof(int), stream);
  int sb = (N + 255) / 256;
  k_count<<<2048, 256, 0, stream>>>(dsts, deg, E, N);
  k_wprep_all<<<20, 256, 0, stream>>>(W1, W2, W3, Wh1, Wh2, Wh3);
  k_partial<<<sb, 256, 0, stream>>>(deg, partials, N);
  k_scan_partials<<<1, 256, 0, stream>>>(partials, sb);
  k_write<<<sb, 256, 0, stream>>>(deg, partials, row_start, cursor, dinv, N);
  k_fill<<<2048, 256, 0, stream>>>(srcs, dsts, cursor, csr, E, N);

  int gb = (N + 63) / 64;  // 64 rows per block (4 waves x 16 rows)
  int nb = (N + 3) / 4;    // 4 waves (nodes) per block

  // Layer 1
  k_gemm_mfma<128, float><<<gb, 256, 0, stream>>>(x, Wh1, dinv, y, N);
  k_agg_ln<<<nb, 256, 0, stream>>>(y, csr, row_start, deg, dinv, b1, g1, be1, h, N);
  // Layer 2
  k_gemm_mfma<128, _Float16><<<gb, 256, 0, stream>>>(h, Wh2, dinv, y, N);
  k_agg_ln<<<nb, 256, 0, stream>>>(y, csr, row_start, deg, dinv, b2, g2, be2, h, N);
  // Layer 3
  k_gemm_mfma<64, _Float16><<<gb, 256, 0, stream>>>(h, Wh3, dinv, y, N);
  k_agg_out<<<nb, 256, 0, stream>>>(y, csr, row_start, deg, dinv, b3, (float*)d_out, N);
}